// Round 9
// baseline (354.607 us; speedup 1.0000x reference)
//
#include <hip/hip_runtime.h>
#include <hip/hip_fp16.h>

#define NN 100000
#define NE 1200000
#define NBUK ((NN + 127) / 128)   // 782
#define NCHUNK 512                // histogram chunks
#define NPROJ ((NN + 63) / 64)    // 1563 proj tiles

typedef _Float16 h8 __attribute__((ext_vector_type(8)));
typedef float f32x4 __attribute__((ext_vector_type(4)));
typedef float f32x2 __attribute__((ext_vector_type(2)));

// ---------------- kernel 1: degree histogram (blocks 0..511) in parallel
// with proj+byp GEMM (blocks 512..): independent work, one dispatch.
__global__ __launch_bounds__(256) void k_fusedA(const int* __restrict__ col,
                                                int* __restrict__ deg,
                                                int* __restrict__ bsum,
                                                const float* __restrict__ X,
                                                const float* __restrict__ projW,
                                                const float* __restrict__ projb,
                                                const float* __restrict__ bypW,
                                                const float* __restrict__ bypb,
                                                _Float16* __restrict__ Yh,
                                                float* __restrict__ bypOut) {
    constexpr int D = 128, RS = D + 8, KS = D / 32;
    __shared__ _Float16 Xh[64 * RS];
    __shared__ _Float16 Wh[64 * RS];
    const int tid = threadIdx.x;

    if (blockIdx.x < NCHUNK) {
        // ---- per-node degree atomics + per-bucket totals (LDS histogram)
        int* lh = (int*)Xh;                       // 782 ints, aliases Xh
        const int per = (NE + NCHUNK - 1) / NCHUNK;
        const int e0 = blockIdx.x * per;
        const int e1 = (e0 + per < NE) ? (e0 + per) : NE;
        for (int i = tid; i < NBUK; i += 256) lh[i] = 0;
        __syncthreads();
        for (int e = e0 + tid; e < e1; e += 256) {
            int c = col[e];
            atomicAdd(&deg[c], 1);
            atomicAdd(&lh[c >> 7], 1);
        }
        __syncthreads();
        for (int b = tid; b < NBUK; b += 256) {
            int v = lh[b];
            if (v) atomicAdd(&bsum[b], v);
        }
        return;
    }

    // ---- proj + byp GEMM (identical math to the anchor's gemmPC)
    const int n0 = (blockIdx.x - NCHUNK) * 64;

    for (int i = tid; i < 64 * (D / 8); i += 256) {
        int j = i / (D / 8), d8 = (i % (D / 8)) * 8;
        const float4* wp = (const float4*)&projW[j * D + d8];
        float4 w0 = wp[0], w1 = wp[1];
        h8 h = { (_Float16)w0.x, (_Float16)w0.y, (_Float16)w0.z, (_Float16)w0.w,
                 (_Float16)w1.x, (_Float16)w1.y, (_Float16)w1.z, (_Float16)w1.w };
        *(h8*)&Wh[j * RS + d8] = h;
    }
    for (int i = tid; i < 64 * (D / 8); i += 256) {
        int nl = i / (D / 8), d8 = (i % (D / 8)) * 8;
        int n = n0 + nl; if (n >= NN) n = NN - 1;
        const float4* xp = (const float4*)&X[(size_t)n * D + d8];
        float4 x0 = xp[0], x1 = xp[1];
        h8 h = { (_Float16)x0.x, (_Float16)x0.y, (_Float16)x0.z, (_Float16)x0.w,
                 (_Float16)x1.x, (_Float16)x1.y, (_Float16)x1.z, (_Float16)x1.w };
        *(h8*)&Xh[nl * RS + d8] = h;
    }
    __syncthreads();

    const int wid = tid >> 6, lane = tid & 63;
    const int lm = lane & 15, lq = lane >> 4;
    const int mBase = wid * 16;

    h8 bfrag[4][KS];
    #pragma unroll
    for (int t = 0; t < 4; ++t)
        #pragma unroll
        for (int s = 0; s < KS; ++s)
            bfrag[t][s] = *(const h8*)&Wh[(t * 16 + lm) * RS + s * 32 + lq * 8];

    h8 bfragB[KS];
    #pragma unroll
    for (int s = 0; s < KS; ++s) {
        if (lm < 3) {
            const float4* wp = (const float4*)&bypW[lm * D + s * 32 + lq * 8];
            float4 w0 = wp[0], w1 = wp[1];
            bfragB[s] = (h8){ (_Float16)w0.x, (_Float16)w0.y, (_Float16)w0.z, (_Float16)w0.w,
                              (_Float16)w1.x, (_Float16)w1.y, (_Float16)w1.z, (_Float16)w1.w };
        } else {
            bfragB[s] = (h8)(_Float16)0;
        }
    }

    f32x4 acc[5] = {};
    #pragma unroll
    for (int s = 0; s < KS; ++s) {
        h8 a = *(const h8*)&Xh[(mBase + lm) * RS + s * 32 + lq * 8];
        #pragma unroll
        for (int t = 0; t < 4; ++t)
            acc[t] = __builtin_amdgcn_mfma_f32_16x16x32_f16(a, bfrag[t][s], acc[t], 0, 0, 0);
        acc[4] = __builtin_amdgcn_mfma_f32_16x16x32_f16(a, bfragB[s], acc[4], 0, 0, 0);
    }

    float bb[4];
    #pragma unroll
    for (int t = 0; t < 4; ++t) bb[t] = projb[t * 16 + lm];
    float bypbv = (lm < 3) ? bypb[lm] : 0.f;
    const int nodeBase = n0 + mBase + lq * 4;

    #pragma unroll
    for (int r = 0; r < 4; ++r) {
        int node = nodeBase + r;
        if (node < NN) {
            #pragma unroll
            for (int t = 0; t < 4; ++t)
                Yh[(size_t)node * 64 + t * 16 + lm] = (_Float16)(acc[t][r] + bb[t]);
            if (lm < 3)
                bypOut[node * 3 + lm] = acc[4][r] + bypbv;
        }
    }
}

// ---------------- off/cur/dinv from deg + fused conv1-msg GEMM ----------------
__global__ __launch_bounds__(256) void k_offM(const int* __restrict__ deg,
                                              const int* __restrict__ bsum,
                                              int* __restrict__ off,
                                              int* __restrict__ cur,
                                              float* __restrict__ dinv,
                                              const _Float16* __restrict__ hA,
                                              const float* __restrict__ W1,
                                              unsigned char* __restrict__ Y8) {
    constexpr int RS2 = 72;
    __shared__ int s[128];
    __shared__ int red[256];
    __shared__ float dinvL[128];
    __shared__ _Float16 Hs[128 * RS2];    // 18432 B
    __shared__ _Float16 WsL[64 * RS2];    // 9216 B
    const int b = blockIdx.x, tid = threadIdx.x;
    const int colBase = b << 7;
    const int nCols = (NN - colBase < 128) ? (NN - colBase) : 128;

    // stage this block's 128 hA rows and W1 (fp32->fp16)
    for (int i = tid; i < 128 * 8; i += 256) {
        int j = i >> 3, d8 = (i & 7) * 8;
        int n = colBase + j; if (n >= NN) n = NN - 1;
        *(h8*)&Hs[j * RS2 + d8] = *(const h8*)&hA[(size_t)n * 64 + d8];
    }
    for (int i = tid; i < 64 * 8; i += 256) {
        int j = i >> 3, d8 = (i & 7) * 8;
        const float4* wp = (const float4*)&W1[j * 64 + d8];
        float4 w0 = wp[0], w1 = wp[1];
        h8 h = { (_Float16)w0.x, (_Float16)w0.y, (_Float16)w0.z, (_Float16)w0.w,
                 (_Float16)w1.x, (_Float16)w1.y, (_Float16)w1.z, (_Float16)w1.w };
        *(h8*)&WsL[j * RS2 + d8] = h;
    }

    // segment base = sum of bucket totals before b
    int ssum = 0;
    for (int i = tid; i < b; i += 256) ssum += bsum[i];
    red[tid] = ssum;
    __syncthreads();
    #pragma unroll
    for (int d = 128; d > 0; d >>= 1) {
        if (tid < d) red[tid] += red[tid + d];
        __syncthreads();
    }
    const int seg0 = red[0];

    // local exclusive scan of deg over 128 nodes
    int dv_ = (tid < nCols) ? deg[colBase + tid] : 0;
    if (tid < 128) s[tid] = dv_;
    __syncthreads();
    #pragma unroll
    for (int d = 1; d < 128; d <<= 1) {
        int t = (tid < 128 && tid >= d) ? s[tid - d] : 0;
        __syncthreads();
        if (tid < 128) s[tid] += t;
        __syncthreads();
    }
    if (tid < 128) {
        float dvv = rsqrtf((float)dv_ + 1.0f);
        dinvL[tid] = dvv;
        if (tid < nCols) {
            int exc = seg0 + s[tid] - dv_;
            off[colBase + tid] = exc;
            cur[colBase + tid] = exc;
            dinv[colBase + tid] = dvv;
        }
    }
    if (b == 0 && tid == 0) off[NN] = NE;
    __syncthreads();   // Hs/WsL staged, dinvL ready

    // conv1-msg GEMM: two 64-row halves, the validated fragment pattern
    const int wid = tid >> 6, lane = tid & 63;
    const int lm = lane & 15, lq = lane >> 4;
    const int mBase = wid * 16;
    h8 cfrag[4][2];
    #pragma unroll
    for (int t = 0; t < 4; ++t)
        #pragma unroll
        for (int sx = 0; sx < 2; ++sx)
            cfrag[t][sx] = *(const h8*)&WsL[(t * 16 + lm) * RS2 + sx * 32 + lq * 8];
    #pragma unroll
    for (int hh = 0; hh < 2; ++hh) {
        const int rb = hh * 64 + mBase;
        f32x4 acc2[4] = {};
        #pragma unroll
        for (int sx = 0; sx < 2; ++sx) {
            h8 a = *(const h8*)&Hs[(rb + lm) * RS2 + sx * 32 + lq * 8];
            #pragma unroll
            for (int t = 0; t < 4; ++t)
                acc2[t] = __builtin_amdgcn_mfma_f32_16x16x32_f16(a, cfrag[t][sx], acc2[t], 0, 0, 0);
        }
        #pragma unroll
        for (int r = 0; r < 4; ++r) {
            int nl = rb + lq * 4 + r;
            int node = colBase + nl;
            if (node < NN) {
                float sdv = dinvL[nl];
                #pragma unroll
                for (int t = 0; t < 4; ++t) {
                    float v = acc2[t][r] * sdv;
                    int pk = __builtin_amdgcn_cvt_pk_fp8_f32(v, v, 0, false);
                    Y8[(size_t)node * 64 + t * 16 + lm] = (unsigned char)(pk & 0xff);
                }
            }
        }
    }
}

// ---------------- edge scatter: csr_row via per-node atomic cursors ----------
__global__ __launch_bounds__(256) void k_scatter(const int* __restrict__ row,
                                                 const int* __restrict__ col,
                                                 int* __restrict__ cur,
                                                 int* __restrict__ csr_row) {
    int e = blockIdx.x * 256 + threadIdx.x;
    const int stride = gridDim.x * 256;
    for (; e < NE; e += stride) {
        int c = col[e], r = row[e];
        int pos = atomicAdd(&cur[c], 1);
        csr_row[pos] = r;
    }
}

// ---------------- pull-aggregation (R1-verbatim, best-measured config):
// 8 lanes/node x 8 bytes, wave-max batch-8 loop, fused next-layer msg GEMM.
template<bool HEAD>
__global__ __launch_bounds__(256) void k_gather(const unsigned char* __restrict__ hB8,
                                                const float* __restrict__ dinv,
                                                const int* __restrict__ off,
                                                const int* __restrict__ csr_row,
                                                const float* __restrict__ convb,
                                                const float* __restrict__ bng,
                                                const float* __restrict__ bnb,
                                                _Float16* __restrict__ hA,
                                                const float* __restrict__ nextW,
                                                unsigned char* __restrict__ Y8,
                                                const float* __restrict__ byp,
                                                const float* __restrict__ headW,
                                                const float* __restrict__ headb,
                                                float* __restrict__ out) {
    constexpr int RS2 = 72;
    __shared__ _Float16 Ws[HEAD ? 1 : 64 * RS2];
    __shared__ _Float16 Hs[HEAD ? 1 : 32 * RS2];
    __shared__ float HWs[HEAD ? 204 : 1];
    const int tid = threadIdx.x;
    if constexpr (HEAD) {
        for (int i = tid; i < 204; i += 256)
            HWs[i] = (i < 201) ? headW[i] : headb[i - 201];
        __syncthreads();
    } else {
        for (int i = tid; i < 64 * 8; i += 256) {
            int j = i >> 3, d8 = (i & 7) * 8;
            const float4* wp = (const float4*)&nextW[j * 64 + d8];
            float4 w0 = wp[0], w1 = wp[1];
            h8 h = { (_Float16)w0.x, (_Float16)w0.y, (_Float16)w0.z, (_Float16)w0.w,
                     (_Float16)w1.x, (_Float16)w1.y, (_Float16)w1.z, (_Float16)w1.w };
            *(h8*)&Ws[j * RS2 + d8] = h;
        }
    }
    const int wid = tid >> 6, lane = tid & 63;
    const int nloc = wid * 8 + (lane >> 3);
    const int n = blockIdx.x * 32 + nloc;        // grid = NN/32 exactly
    const int oct = lane & 7;
    const int f0 = oct * 8;

    const int e0 = off[n];
    const int deg = off[n + 1] - e0;
    int m = deg;
    #pragma unroll
    for (int mask = 8; mask < 64; mask <<= 1) {
        int o = __shfl_xor(m, mask, 64);
        m = (o > m) ? o : m;
    }

    const uint2* rows8 = (const uint2*)hB8;   // 8 uint2 per node row
    float acc[8] = {0, 0, 0, 0, 0, 0, 0, 0};
    uint2 selfw = rows8[(size_t)n * 8 + oct];
    {
        f32x2 p0 = __builtin_amdgcn_cvt_pk_f32_fp8(selfw.x, false);
        f32x2 p1 = __builtin_amdgcn_cvt_pk_f32_fp8(selfw.x, true);
        f32x2 p2 = __builtin_amdgcn_cvt_pk_f32_fp8(selfw.y, false);
        f32x2 p3 = __builtin_amdgcn_cvt_pk_f32_fp8(selfw.y, true);
        acc[0] += p0.x; acc[1] += p0.y; acc[2] += p1.x; acc[3] += p1.y;
        acc[4] += p2.x; acc[5] += p2.y; acc[6] += p3.x; acc[7] += p3.y;
    }
    for (int it = 0; it < m; it += 8) {
        uint2 w[8];
        #pragma unroll
        for (int q = 0; q < 8; ++q) {
            bool vq = it + q < deg;
            int rq = csr_row[vq ? e0 + it + q : 0];
            w[q] = rows8[(size_t)rq * 8 + oct];
            if (!vq) { w[q].x = 0; w[q].y = 0; }
        }
        #pragma unroll
        for (int q = 0; q < 8; ++q) {
            f32x2 p0 = __builtin_amdgcn_cvt_pk_f32_fp8(w[q].x, false);
            f32x2 p1 = __builtin_amdgcn_cvt_pk_f32_fp8(w[q].x, true);
            f32x2 p2 = __builtin_amdgcn_cvt_pk_f32_fp8(w[q].y, false);
            f32x2 p3 = __builtin_amdgcn_cvt_pk_f32_fp8(w[q].y, true);
            acc[0] += p0.x; acc[1] += p0.y; acc[2] += p1.x; acc[3] += p1.y;
            acc[4] += p2.x; acc[5] += p2.y; acc[6] += p3.x; acc[7] += p3.y;
        }
    }

    const float dv = dinv[n];
    const float bnscale = rsqrtf(1.0f + 1e-5f);
    const float4 cb0 = *(const float4*)&convb[f0], cb1 = *(const float4*)&convb[f0 + 4];
    const float4 g0  = *(const float4*)&bng[f0],  g1  = *(const float4*)&bng[f0 + 4];
    const float4 b0_ = *(const float4*)&bnb[f0],  b1_ = *(const float4*)&bnb[f0 + 4];
    const float cb[8] = { cb0.x, cb0.y, cb0.z, cb0.w, cb1.x, cb1.y, cb1.z, cb1.w };
    const float gg[8] = { g0.x, g0.y, g0.z, g0.w, g1.x, g1.y, g1.z, g1.w };
    const float bb[8] = { b0_.x, b0_.y, b0_.z, b0_.w, b1_.x, b1_.y, b1_.z, b1_.w };
    float v[8];
    #pragma unroll
    for (int j = 0; j < 8; ++j)
        v[j] = fmaxf((acc[j] * dv + cb[j]) * (gg[j] * bnscale) + bb[j], 0.0f);

    if constexpr (!HEAD) {
        size_t o = ((size_t)n << 6) + f0;
        h8 old = *(const h8*)&hA[o];
        #pragma unroll
        for (int j = 0; j < 8; ++j) v[j] += (float)old[j];
        h8 res = { (_Float16)v[0], (_Float16)v[1], (_Float16)v[2], (_Float16)v[3],
                   (_Float16)v[4], (_Float16)v[5], (_Float16)v[6], (_Float16)v[7] };
        *(h8*)&hA[o] = res;
        *(h8*)&Hs[nloc * RS2 + f0] = res;
        __syncthreads();

        // fused next-layer msg GEMM: Y8 = fp8((Hs @ Ws.T) * dinv), 32x64 @ 64x64
        const int lm = lane & 15, lq = lane >> 4;
        const int mt = (wid & 1) * 16;     // M-tile (node rows)
        const int nt = (wid >> 1) * 32;    // N-cols base (2 tiles of 16)
        h8 afrag[2], bfrag[2][2];
        #pragma unroll
        for (int s = 0; s < 2; ++s)
            afrag[s] = *(const h8*)&Hs[(mt + lm) * RS2 + s * 32 + lq * 8];
        #pragma unroll
        for (int t = 0; t < 2; ++t)
            #pragma unroll
            for (int s = 0; s < 2; ++s)
                bfrag[t][s] = *(const h8*)&Ws[(nt + t * 16 + lm) * RS2 + s * 32 + lq * 8];
        f32x4 acc2[2] = {};
        #pragma unroll
        for (int s = 0; s < 2; ++s)
            #pragma unroll
            for (int t = 0; t < 2; ++t)
                acc2[t] = __builtin_amdgcn_mfma_f32_16x16x32_f16(afrag[s], bfrag[t][s], acc2[t], 0, 0, 0);
        const int nodeBase = blockIdx.x * 32 + mt + lq * 4;
        #pragma unroll
        for (int r = 0; r < 4; ++r) {
            int node = nodeBase + r;
            float sdv = dinv[node];
            #pragma unroll
            for (int t = 0; t < 2; ++t) {
                float vv = acc2[t][r] * sdv;
                int pk = __builtin_amdgcn_cvt_pk_fp8_f32(vv, vv, 0, false);
                Y8[(size_t)node * 64 + nt + t * 16 + lm] = (unsigned char)(pk & 0xff);
            }
        }
    } else {
        float p[3];
        #pragma unroll
        for (int o = 0; o < 3; ++o) {
            float t = 0.f;
            #pragma unroll
            for (int j = 0; j < 8; ++j) t += v[j] * HWs[o * 67 + f0 + j];
            p[o] = t;
        }
        #pragma unroll
        for (int mask = 1; mask < 8; mask <<= 1) {
            #pragma unroll
            for (int o = 0; o < 3; ++o) p[o] += __shfl_xor(p[o], mask, 64);
        }
        if (oct == 0) {
            float by0 = byp[n * 3], by1 = byp[n * 3 + 1], by2 = byp[n * 3 + 2];
            #pragma unroll
            for (int o = 0; o < 3; ++o)
                p[o] += by0 * HWs[o * 67 + 64] + by1 * HWs[o * 67 + 65] + by2 * HWs[o * 67 + 66]
                      + HWs[201 + o];
            float kappa = fminf(fmaxf(p[0] * 5.0f + 2.5f, 0.2f), 10.0f);
            float tau   = fminf(fmaxf(p[2] + 0.5f, 0.05f), 2.0f);
            out[(size_t)n * 3]     = kappa;
            out[(size_t)n * 3 + 1] = p[1];
            out[(size_t)n * 3 + 2] = tau;
        }
    }
}

extern "C" void kernel_launch(void* const* d_in, const int* in_sizes, int n_in,
                              void* d_out, int out_size, void* d_ws, size_t ws_size,
                              hipStream_t stream) {
    const float* x     = (const float*)d_in[0];
    const int*   ei    = (const int*)d_in[1];
    const int*   row   = ei;
    const int*   col   = ei + NE;
    const float* projW = (const float*)d_in[2];
    const float* projb = (const float*)d_in[3];
    const float* convW[3] = { (const float*)d_in[4], (const float*)d_in[8],  (const float*)d_in[12] };
    const float* convb[3] = { (const float*)d_in[5], (const float*)d_in[9],  (const float*)d_in[13] };
    const float* bng[3]   = { (const float*)d_in[6], (const float*)d_in[10], (const float*)d_in[14] };
    const float* bnb[3]   = { (const float*)d_in[7], (const float*)d_in[11], (const float*)d_in[15] };
    const float* bypW  = (const float*)d_in[16];
    const float* bypb  = (const float*)d_in[17];
    const float* headW = (const float*)d_in[18];
    const float* headb = (const float*)d_in[19];
    float* out = (float*)d_out;

    float*    ws   = (float*)d_ws;
    float*    dinv = ws;                                   // 102400 floats
    _Float16* hAh  = (_Float16*)(ws + 102400);             // NN*64 fp16
    unsigned char* hB8a = (unsigned char*)(hAh + (size_t)NN * 64);  // NN*64 bytes fp8
    float*    byp  = (float*)(hB8a + (size_t)NN * 64);     // NN*3 (+pad 300032)
    int*      off     = (int*)(byp + 300032);              // NN+1 (pad 100096)
    int*      csr_row = off + 100096;                      // NE
    int*      deg     = csr_row + NE;                      // 100096
    int*      bsum    = deg + 100096;                      // 784
    int*      cur     = bsum + 784;                        // 100096
    unsigned char* hB8b = (unsigned char*)(cur + 100096);  // NN*64 fp8

    // zero deg + bsum (contiguous)
    hipMemsetAsync(deg, 0, (100096 + 784) * sizeof(int), stream);

    // 1) degree histogram || proj+byp GEMM (independent, one dispatch)
    k_fusedA<<<NCHUNK + NPROJ, 256, 0, stream>>>(
        col, deg, bsum, x, projW, projb, bypW, bypb, hAh, byp);
    // 2) off/cur/dinv from deg + fused conv1-msg GEMM -> hB8a
    k_offM<<<NBUK, 256, 0, stream>>>(deg, bsum, off, cur, dinv,
                                     hAh, convW[0], hB8a);
    // 3) edge scatter -> csr_row (within-node order nondeterministic;
    //    fp32 sum-order jitter ~1e-6, far below the 0.0625 threshold)
    k_scatter<<<2048, 256, 0, stream>>>(row, col, cur, csr_row);

    // 4-6) gather layers (R8-verbatim config)
    k_gather<false><<<NN / 32, 256, 0, stream>>>(
        hB8a, dinv, off, csr_row, convb[0], bng[0], bnb[0], hAh,
        convW[1], hB8b, nullptr, nullptr, nullptr, nullptr);
    k_gather<false><<<NN / 32, 256, 0, stream>>>(
        hB8b, dinv, off, csr_row, convb[1], bng[1], bnb[1], hAh,
        convW[2], hB8a, nullptr, nullptr, nullptr, nullptr);
    k_gather<true><<<NN / 32, 256, 0, stream>>>(
        hB8a, dinv, off, csr_row, convb[2], bng[2], bnb[2], nullptr,
        nullptr, nullptr, byp, headW, headb, out);
}

// Round 11
// 245.179 us; speedup vs baseline: 1.4463x; 1.4463x over previous
//
#include <hip/hip_runtime.h>
#include <hip/hip_fp16.h>

#define NN 100000
#define NE 1200000
#define NBUK ((NN + 127) / 128)   // 782
#define NCHUNK 512                // chunks in bucket passes
#define NPROJ ((NN + 63) / 64)    // 1563 proj tiles

typedef _Float16 h8 __attribute__((ext_vector_type(8)));
typedef float f32x4 __attribute__((ext_vector_type(4)));
typedef float f32x2 __attribute__((ext_vector_type(2)));

// ---------------- kernel 1: bucketA histogram (blocks 0..511) in parallel
// with proj+byp GEMM (blocks 512..): independent work, one dispatch.
__global__ __launch_bounds__(256) void k_fusedA(const int* __restrict__ col,
                                                int* __restrict__ blkcnt,
                                                const float* __restrict__ X,
                                                const float* __restrict__ projW,
                                                const float* __restrict__ projb,
                                                const float* __restrict__ bypW,
                                                const float* __restrict__ bypb,
                                                _Float16* __restrict__ Yh,
                                                float* __restrict__ bypOut) {
    constexpr int D = 128, RS = D + 8, KS = D / 32;
    __shared__ _Float16 Xh[64 * RS];
    __shared__ _Float16 Wh[64 * RS];
    const int tid = threadIdx.x;

    if (blockIdx.x < NCHUNK) {
        // ---- bucketA: per-chunk histogram of col into blkcnt
        int* lh = (int*)Xh;                       // 782 ints, aliases Xh
        const int per = (NE + NCHUNK - 1) / NCHUNK;
        const int e0 = blockIdx.x * per;
        const int e1 = (e0 + per < NE) ? (e0 + per) : NE;
        for (int i = tid; i < NBUK; i += 256) lh[i] = 0;
        __syncthreads();
        for (int e = e0 + tid; e < e1; e += 256)
            atomicAdd(&lh[col[e] >> 7], 1);
        __syncthreads();
        for (int b = tid; b < NBUK; b += 256)
            blkcnt[b * NCHUNK + blockIdx.x] = lh[b];
        return;
    }

    // ---- proj + byp GEMM (identical math to the 258-us anchor's gemmPC,
    // minus the conv1-msg part which needs dinv)
    const int n0 = (blockIdx.x - NCHUNK) * 64;

    for (int i = tid; i < 64 * (D / 8); i += 256) {
        int j = i / (D / 8), d8 = (i % (D / 8)) * 8;
        const float4* wp = (const float4*)&projW[j * D + d8];
        float4 w0 = wp[0], w1 = wp[1];
        h8 h = { (_Float16)w0.x, (_Float16)w0.y, (_Float16)w0.z, (_Float16)w0.w,
                 (_Float16)w1.x, (_Float16)w1.y, (_Float16)w1.z, (_Float16)w1.w };
        *(h8*)&Wh[j * RS + d8] = h;
    }
    for (int i = tid; i < 64 * (D / 8); i += 256) {
        int nl = i / (D / 8), d8 = (i % (D / 8)) * 8;
        int n = n0 + nl; if (n >= NN) n = NN - 1;
        const float4* xp = (const float4*)&X[(size_t)n * D + d8];
        float4 x0 = xp[0], x1 = xp[1];
        h8 h = { (_Float16)x0.x, (_Float16)x0.y, (_Float16)x0.z, (_Float16)x0.w,
                 (_Float16)x1.x, (_Float16)x1.y, (_Float16)x1.z, (_Float16)x1.w };
        *(h8*)&Xh[nl * RS + d8] = h;
    }
    __syncthreads();

    const int wid = tid >> 6, lane = tid & 63;
    const int lm = lane & 15, lq = lane >> 4;
    const int mBase = wid * 16;

    h8 bfrag[4][KS];
    #pragma unroll
    for (int t = 0; t < 4; ++t)
        #pragma unroll
        for (int s = 0; s < KS; ++s)
            bfrag[t][s] = *(const h8*)&Wh[(t * 16 + lm) * RS + s * 32 + lq * 8];

    h8 bfragB[KS];
    #pragma unroll
    for (int s = 0; s < KS; ++s) {
        if (lm < 3) {
            const float4* wp = (const float4*)&bypW[lm * D + s * 32 + lq * 8];
            float4 w0 = wp[0], w1 = wp[1];
            bfragB[s] = (h8){ (_Float16)w0.x, (_Float16)w0.y, (_Float16)w0.z, (_Float16)w0.w,
                              (_Float16)w1.x, (_Float16)w1.y, (_Float16)w1.z, (_Float16)w1.w };
        } else {
            bfragB[s] = (h8)(_Float16)0;
        }
    }

    f32x4 acc[5] = {};
    #pragma unroll
    for (int s = 0; s < KS; ++s) {
        h8 a = *(const h8*)&Xh[(mBase + lm) * RS + s * 32 + lq * 8];
        #pragma unroll
        for (int t = 0; t < 4; ++t)
            acc[t] = __builtin_amdgcn_mfma_f32_16x16x32_f16(a, bfrag[t][s], acc[t], 0, 0, 0);
        acc[4] = __builtin_amdgcn_mfma_f32_16x16x32_f16(a, bfragB[s], acc[4], 0, 0, 0);
    }

    float bb[4];
    #pragma unroll
    for (int t = 0; t < 4; ++t) bb[t] = projb[t * 16 + lm];
    float bypbv = (lm < 3) ? bypb[lm] : 0.f;
    const int nodeBase = n0 + mBase + lq * 4;

    #pragma unroll
    for (int r = 0; r < 4; ++r) {
        int node = nodeBase + r;
        if (node < NN) {
            #pragma unroll
            for (int t = 0; t < 4; ++t)
                Yh[(size_t)node * 64 + t * 16 + lm] = (_Float16)(acc[t][r] + bb[t]);
            if (lm < 3)
                bypOut[node * 3 + lm] = acc[4][r] + bypbv;
        }
    }
}

// grid = NBUK; exclusive scan of the 512 chunk counts of bucket b (in place),
// plus bucket total -> bcnt[b]
__global__ __launch_bounds__(1024) void k_scanAll(int* __restrict__ blkcnt,
                                                  int* __restrict__ bcnt) {
    __shared__ int s[1024];
    const int b = blockIdx.x, tid = threadIdx.x;
    int v = (tid < NCHUNK) ? blkcnt[b * NCHUNK + tid] : 0;
    s[tid] = v;
    __syncthreads();
    #pragma unroll
    for (int d = 1; d < 1024; d <<= 1) {
        int t = (tid >= d) ? s[tid - d] : 0;
        __syncthreads();
        s[tid] += t;
        __syncthreads();
    }
    if (tid < NCHUNK) blkcnt[b * NCHUNK + tid] = s[tid] - v;
    if (tid == 1023) bcnt[b] = s[1023];
}

__global__ __launch_bounds__(256) void k_bucketB(const int* __restrict__ row,
                                                 const int* __restrict__ col,
                                                 const int* __restrict__ bcnt,
                                                 const int* __restrict__ blkcnt,
                                                 unsigned* __restrict__ tmp) {
    __shared__ int lh[NBUK];
    __shared__ int part[256];
    const int tid = threadIdx.x;
    // local exclusive scan of bucket totals (782 values, 4 per thread)
    int loc[4]; int sum = 0;
    #pragma unroll
    for (int j = 0; j < 4; ++j) {
        int idx = tid * 4 + j;
        loc[j] = sum;
        sum += (idx < NBUK) ? bcnt[idx] : 0;
    }
    part[tid] = sum;
    __syncthreads();
    #pragma unroll
    for (int d = 1; d < 256; d <<= 1) {
        int t = (tid >= d) ? part[tid - d] : 0;
        __syncthreads();
        part[tid] += t;
        __syncthreads();
    }
    const int excl = part[tid] - sum;
    #pragma unroll
    for (int j = 0; j < 4; ++j) {
        int idx = tid * 4 + j;
        if (idx < NBUK)
            lh[idx] = excl + loc[j] + blkcnt[idx * NCHUNK + blockIdx.x];
    }
    __syncthreads();
    const int per = (NE + NCHUNK - 1) / NCHUNK;
    const int e0 = blockIdx.x * per;
    const int e1 = (e0 + per < NE) ? (e0 + per) : NE;
    for (int e = e0 + tid; e < e1; e += 256) {
        int c = col[e], r = row[e];
        int pos = atomicAdd(&lh[c >> 7], 1);
        tmp[pos] = ((unsigned)r << 7) | (unsigned)(c & 127);
    }
}

// ---------------- build (CSR for 128 cols) + fused conv1-msg GEMM:
// hB8a[n] = fp8((hA[n] @ W1^T) * dinv[n]) for this block's 128 nodes.
__global__ __launch_bounds__(256) void k_buildM(const unsigned* __restrict__ tmp,
                                                const int* __restrict__ bcnt,
                                                int* __restrict__ off,
                                                float* __restrict__ dinv,
                                                int* __restrict__ csr_row,
                                                const _Float16* __restrict__ hA,
                                                const float* __restrict__ W1,
                                                unsigned char* __restrict__ Y8) {
    constexpr int RS2 = 72;
    __shared__ int cnt[128], s[128], cur[128];
    __shared__ int red[256];
    __shared__ float dinvL[128];
    __shared__ _Float16 Hs[128 * RS2];    // 18432 B
    __shared__ _Float16 WsL[64 * RS2];    // 9216 B
    const int b = blockIdx.x, tid = threadIdx.x;

    // stage this block's 128 hA rows (coalesced 16B/lane) and W1 (fp32->fp16)
    for (int i = tid; i < 128 * 8; i += 256) {
        int j = i >> 3, d8 = (i & 7) * 8;
        int n = (b << 7) + j; if (n >= NN) n = NN - 1;
        *(h8*)&Hs[j * RS2 + d8] = *(const h8*)&hA[(size_t)n * 64 + d8];
    }
    for (int i = tid; i < 64 * 8; i += 256) {
        int j = i >> 3, d8 = (i & 7) * 8;
        const float4* wp = (const float4*)&W1[j * 64 + d8];
        float4 w0 = wp[0], w1 = wp[1];
        h8 h = { (_Float16)w0.x, (_Float16)w0.y, (_Float16)w0.z, (_Float16)w0.w,
                 (_Float16)w1.x, (_Float16)w1.y, (_Float16)w1.z, (_Float16)w1.w };
        *(h8*)&WsL[j * RS2 + d8] = h;
    }

    // segment base = sum of bucket totals before b
    int ssum = 0;
    for (int i = tid; i < b; i += 256) ssum += bcnt[i];
    red[tid] = ssum;
    __syncthreads();
    #pragma unroll
    for (int d = 128; d > 0; d >>= 1) {
        if (tid < d) red[tid] += red[tid + d];
        __syncthreads();
    }
    const int seg0 = red[0];
    const int seg1 = seg0 + bcnt[b];
    const int colBase = b << 7;
    const int nCols = (NN - colBase < 128) ? (NN - colBase) : 128;
    if (tid < 128) cnt[tid] = 0;
    __syncthreads();
    for (int i = seg0 + tid; i < seg1; i += 256)
        atomicAdd(&cnt[tmp[i] & 127], 1);
    __syncthreads();
    if (tid < 128) s[tid] = cnt[tid];
    __syncthreads();
    #pragma unroll
    for (int d = 1; d < 128; d <<= 1) {
        int t = (tid < 128 && tid >= d) ? s[tid - d] : 0;
        __syncthreads();
        if (tid < 128) s[tid] += t;
        __syncthreads();
    }
    if (tid < 128) {
        float dv = rsqrtf((float)cnt[tid] + 1.0f);
        dinvL[tid] = dv;
        if (tid < nCols) {
            int exc = seg0 + s[tid] - cnt[tid];
            off[colBase + tid] = exc;
            cur[tid] = exc;
            dinv[colBase + tid] = dv;
        }
    }
    if (b == 0 && tid == 0) off[NN] = NE;
    __syncthreads();
    for (int i = seg0 + tid; i < seg1; i += 256) {
        unsigned v = tmp[i];
        int pos = atomicAdd(&cur[v & 127u], 1);
        csr_row[pos] = (int)(v >> 7);
    }
    __syncthreads();   // Hs/WsL staged, dinvL ready

    // conv1-msg GEMM: two 64-row halves, gemmPC's exact fragment pattern
    const int wid = tid >> 6, lane = tid & 63;
    const int lm = lane & 15, lq = lane >> 4;
    const int mBase = wid * 16;
    h8 cfrag[4][2];
    #pragma unroll
    for (int t = 0; t < 4; ++t)
        #pragma unroll
        for (int sx = 0; sx < 2; ++sx)
            cfrag[t][sx] = *(const h8*)&WsL[(t * 16 + lm) * RS2 + sx * 32 + lq * 8];
    #pragma unroll
    for (int hh = 0; hh < 2; ++hh) {
        const int rb = hh * 64 + mBase;
        f32x4 acc2[4] = {};
        #pragma unroll
        for (int sx = 0; sx < 2; ++sx) {
            h8 a = *(const h8*)&Hs[(rb + lm) * RS2 + sx * 32 + lq * 8];
            #pragma unroll
            for (int t = 0; t < 4; ++t)
                acc2[t] = __builtin_amdgcn_mfma_f32_16x16x32_f16(a, cfrag[t][sx], acc2[t], 0, 0, 0);
        }
        #pragma unroll
        for (int r = 0; r < 4; ++r) {
            int nl = rb + lq * 4 + r;
            int node = colBase + nl;
            if (node < NN) {
                float sdv = dinvL[nl];
                #pragma unroll
                for (int t = 0; t < 4; ++t) {
                    float v = acc2[t][r] * sdv;
                    int pk = __builtin_amdgcn_cvt_pk_fp8_f32(v, v, 0, false);
                    Y8[(size_t)node * 64 + t * 16 + lm] = (unsigned char)(pk & 0xff);
                }
            }
        }
    }
}

// ---------------- pull-aggregation (R8 structure) with packed f32x2
// accumulation: 4 cvt_pk + 4 v_pk_add_f32 per uint2 (was 4 cvt + 8 v_add).
// Per-feature sum order unchanged -> bit-identical output.
template<bool HEAD>
__global__ __launch_bounds__(256) void k_gather(const unsigned char* __restrict__ hB8,
                                                const float* __restrict__ dinv,
                                                const int* __restrict__ off,
                                                const int* __restrict__ csr_row,
                                                const float* __restrict__ convb,
                                                const float* __restrict__ bng,
                                                const float* __restrict__ bnb,
                                                _Float16* __restrict__ hA,
                                                const float* __restrict__ nextW,
                                                unsigned char* __restrict__ Y8,
                                                const float* __restrict__ byp,
                                                const float* __restrict__ headW,
                                                const float* __restrict__ headb,
                                                float* __restrict__ out) {
    constexpr int RS2 = 72;
    __shared__ _Float16 Ws[HEAD ? 1 : 64 * RS2];
    __shared__ _Float16 Hs[HEAD ? 1 : 32 * RS2];
    __shared__ float HWs[HEAD ? 204 : 1];
    const int tid = threadIdx.x;
    if constexpr (HEAD) {
        for (int i = tid; i < 204; i += 256)
            HWs[i] = (i < 201) ? headW[i] : headb[i - 201];
        __syncthreads();
    } else {
        for (int i = tid; i < 64 * 8; i += 256) {
            int j = i >> 3, d8 = (i & 7) * 8;
            const float4* wp = (const float4*)&nextW[j * 64 + d8];
            float4 w0 = wp[0], w1 = wp[1];
            h8 h = { (_Float16)w0.x, (_Float16)w0.y, (_Float16)w0.z, (_Float16)w0.w,
                     (_Float16)w1.x, (_Float16)w1.y, (_Float16)w1.z, (_Float16)w1.w };
            *(h8*)&Ws[j * RS2 + d8] = h;
        }
    }
    const int wid = tid >> 6, lane = tid & 63;
    const int nloc = wid * 8 + (lane >> 3);
    const int n = blockIdx.x * 32 + nloc;        // grid = NN/32 exactly
    const int oct = lane & 7;
    const int f0 = oct * 8;

    const int e0 = off[n];
    const int deg = off[n + 1] - e0;
    int m = deg;
    #pragma unroll
    for (int mask = 8; mask < 64; mask <<= 1) {
        int o = __shfl_xor(m, mask, 64);
        m = (o > m) ? o : m;
    }

    const uint2* rows8 = (const uint2*)hB8;   // 8 uint2 per node row
    f32x2 acc[4] = {};                        // packed pairs: feats {0,1},{2,3},{4,5},{6,7}
    {
        uint2 selfw = rows8[(size_t)n * 8 + oct];
        acc[0] += __builtin_amdgcn_cvt_pk_f32_fp8(selfw.x, false);
        acc[1] += __builtin_amdgcn_cvt_pk_f32_fp8(selfw.x, true);
        acc[2] += __builtin_amdgcn_cvt_pk_f32_fp8(selfw.y, false);
        acc[3] += __builtin_amdgcn_cvt_pk_f32_fp8(selfw.y, true);
    }
    for (int it = 0; it < m; it += 8) {
        uint2 w[8];
        #pragma unroll
        for (int q = 0; q < 8; ++q) {
            bool vq = it + q < deg;
            int rq = csr_row[vq ? e0 + it + q : 0];
            w[q] = rows8[(size_t)rq * 8 + oct];
            if (!vq) { w[q].x = 0; w[q].y = 0; }
        }
        #pragma unroll
        for (int q = 0; q < 8; ++q) {
            acc[0] += __builtin_amdgcn_cvt_pk_f32_fp8(w[q].x, false);
            acc[1] += __builtin_amdgcn_cvt_pk_f32_fp8(w[q].x, true);
            acc[2] += __builtin_amdgcn_cvt_pk_f32_fp8(w[q].y, false);
            acc[3] += __builtin_amdgcn_cvt_pk_f32_fp8(w[q].y, true);
        }
    }

    const float dv = dinv[n];
    const float bnscale = rsqrtf(1.0f + 1e-5f);
    const float4 cb0 = *(const float4*)&convb[f0], cb1 = *(const float4*)&convb[f0 + 4];
    const float4 g0  = *(const float4*)&bng[f0],  g1  = *(const float4*)&bng[f0 + 4];
    const float4 b0_ = *(const float4*)&bnb[f0],  b1_ = *(const float4*)&bnb[f0 + 4];
    const float cb[8] = { cb0.x, cb0.y, cb0.z, cb0.w, cb1.x, cb1.y, cb1.z, cb1.w };
    const float gg[8] = { g0.x, g0.y, g0.z, g0.w, g1.x, g1.y, g1.z, g1.w };
    const float bb[8] = { b0_.x, b0_.y, b0_.z, b0_.w, b1_.x, b1_.y, b1_.z, b1_.w };
    float v[8];
    #pragma unroll
    for (int j = 0; j < 8; ++j)
        v[j] = fmaxf((acc[j >> 1][j & 1] * dv + cb[j]) * (gg[j] * bnscale) + bb[j], 0.0f);

    if constexpr (!HEAD) {
        size_t o = ((size_t)n << 6) + f0;
        h8 old = *(const h8*)&hA[o];
        #pragma unroll
        for (int j = 0; j < 8; ++j) v[j] += (float)old[j];
        h8 res = { (_Float16)v[0], (_Float16)v[1], (_Float16)v[2], (_Float16)v[3],
                   (_Float16)v[4], (_Float16)v[5], (_Float16)v[6], (_Float16)v[7] };
        *(h8*)&hA[o] = res;
        *(h8*)&Hs[nloc * RS2 + f0] = res;
        __syncthreads();

        // fused next-layer msg GEMM: Y8 = fp8((Hs @ Ws.T) * dinv), 32x64 @ 64x64
        const int lm = lane & 15, lq = lane >> 4;
        const int mt = (wid & 1) * 16;     // M-tile (node rows)
        const int nt = (wid >> 1) * 32;    // N-cols base (2 tiles of 16)
        h8 afrag[2], bfrag[2][2];
        #pragma unroll
        for (int s = 0; s < 2; ++s)
            afrag[s] = *(const h8*)&Hs[(mt + lm) * RS2 + s * 32 + lq * 8];
        #pragma unroll
        for (int t = 0; t < 2; ++t)
            #pragma unroll
            for (int s = 0; s < 2; ++s)
                bfrag[t][s] = *(const h8*)&Ws[(nt + t * 16 + lm) * RS2 + s * 32 + lq * 8];
        f32x4 acc2[2] = {};
        #pragma unroll
        for (int s = 0; s < 2; ++s)
            #pragma unroll
            for (int t = 0; t < 2; ++t)
                acc2[t] = __builtin_amdgcn_mfma_f32_16x16x32_f16(afrag[s], bfrag[t][s], acc2[t], 0, 0, 0);
        const int nodeBase = blockIdx.x * 32 + mt + lq * 4;
        #pragma unroll
        for (int r = 0; r < 4; ++r) {
            int node = nodeBase + r;
            float sdv = dinv[node];
            #pragma unroll
            for (int t = 0; t < 2; ++t) {
                float vv = acc2[t][r] * sdv;
                int pk = __builtin_amdgcn_cvt_pk_fp8_f32(vv, vv, 0, false);
                Y8[(size_t)node * 64 + nt + t * 16 + lm] = (unsigned char)(pk & 0xff);
            }
        }
    } else {
        float p[3];
        #pragma unroll
        for (int o = 0; o < 3; ++o) {
            float t = 0.f;
            #pragma unroll
            for (int j = 0; j < 8; ++j) t += v[j] * HWs[o * 67 + f0 + j];
            p[o] = t;
        }
        #pragma unroll
        for (int mask = 1; mask < 8; mask <<= 1) {
            #pragma unroll
            for (int o = 0; o < 3; ++o) p[o] += __shfl_xor(p[o], mask, 64);
        }
        if (oct == 0) {
            float by0 = byp[n * 3], by1 = byp[n * 3 + 1], by2 = byp[n * 3 + 2];
            #pragma unroll
            for (int o = 0; o < 3; ++o)
                p[o] += by0 * HWs[o * 67 + 64] + by1 * HWs[o * 67 + 65] + by2 * HWs[o * 67 + 66]
                      + HWs[201 + o];
            float kappa = fminf(fmaxf(p[0] * 5.0f + 2.5f, 0.2f), 10.0f);
            float tau   = fminf(fmaxf(p[2] + 0.5f, 0.05f), 2.0f);
            out[(size_t)n * 3]     = kappa;
            out[(size_t)n * 3 + 1] = p[1];
            out[(size_t)n * 3 + 2] = tau;
        }
    }
}

extern "C" void kernel_launch(void* const* d_in, const int* in_sizes, int n_in,
                              void* d_out, int out_size, void* d_ws, size_t ws_size,
                              hipStream_t stream) {
    const float* x     = (const float*)d_in[0];
    const int*   ei    = (const int*)d_in[1];
    const int*   row   = ei;
    const int*   col   = ei + NE;
    const float* projW = (const float*)d_in[2];
    const float* projb = (const float*)d_in[3];
    const float* convW[3] = { (const float*)d_in[4], (const float*)d_in[8],  (const float*)d_in[12] };
    const float* convb[3] = { (const float*)d_in[5], (const float*)d_in[9],  (const float*)d_in[13] };
    const float* bng[3]   = { (const float*)d_in[6], (const float*)d_in[10], (const float*)d_in[14] };
    const float* bnb[3]   = { (const float*)d_in[7], (const float*)d_in[11], (const float*)d_in[15] };
    const float* bypW  = (const float*)d_in[16];
    const float* bypb  = (const float*)d_in[17];
    const float* headW = (const float*)d_in[18];
    const float* headb = (const float*)d_in[19];
    float* out = (float*)d_out;

    float*    ws   = (float*)d_ws;
    float*    dinv = ws;                                   // 102400 floats
    _Float16* hAh  = (_Float16*)(ws + 102400);             // NN*64 fp16
    unsigned char* hB8a = (unsigned char*)(hAh + (size_t)NN * 64);  // NN*64 bytes fp8
    float*    byp  = (float*)(hB8a + (size_t)NN * 64);     // NN*3 (+pad 300032)
    int*      off     = (int*)(byp + 300032);              // NN+1 (pad 100096)
    int*      csr_row = off + 100096;                      // NE
    int*      bcnt    = csr_row + NE;                      // NBUK+1 (pad 784)
    int*      blkcnt  = bcnt + 784;                        // NBUK*NCHUNK
    unsigned char* hB8b = (unsigned char*)(blkcnt + (size_t)NBUK * NCHUNK);  // NN*64 fp8
    unsigned* tmp     = (unsigned*)(hB8b + (size_t)NN * 64);  // NE (own region)

    // 1) bucketA histogram || proj+byp GEMM (independent, one dispatch)
    k_fusedA<<<NCHUNK + NPROJ, 256, 0, stream>>>(
        col, blkcnt, x, projW, projb, bypW, bypb, hAh, byp);
    // 2) per-bucket chunk scan + bucket totals
    k_scanAll<<<NBUK, 1024, 0, stream>>>(blkcnt, bcnt);
    // 3) scatter into bucketed tmp (local scan of totals)
    k_bucketB<<<NCHUNK, 256, 0, stream>>>(row, col, bcnt, blkcnt, tmp);
    // 4) CSR build + fused conv1-msg GEMM -> hB8a
    k_buildM<<<NBUK, 256, 0, stream>>>(tmp, bcnt, off, dinv, csr_row,
                                       hAh, convW[0], hB8a);

    // 5-7) gather layers
    k_gather<false><<<NN / 32, 256, 0, stream>>>(
        hB8a, dinv, off, csr_row, convb[0], bng[0], bnb[0], hAh,
        convW[1], hB8b, nullptr, nullptr, nullptr, nullptr);
    k_gather<false><<<NN / 32, 256, 0, stream>>>(
        hB8b, dinv, off, csr_row, convb[1], bng[1], bnb[1], hAh,
        convW[2], hB8a, nullptr, nullptr, nullptr, nullptr);
    k_gather<true><<<NN / 32, 256, 0, stream>>>(
        hB8a, dinv, off, csr_row, convb[2], bng[2], bnb[2], nullptr,
        nullptr, nullptr, byp, headW, headb, out);
}